// Round 1
// baseline (2994.080 us; speedup 1.0000x reference)
//
#include <hip/hip_runtime.h>
#include <hip/hip_bf16.h>
#include <cstdint>

// Problem constants (fixed by reference)
#define Bsz   64
#define Nsz   1024
#define D2    1024   // 2*NHID
#define D3    1536   // 3*NHID
#define DA_   350
#define R_    30
#define MLPH  2048
#define KMLP  46080  // R*3*NHID
#define S1LD  352    // padded leading dim for s1 buffer

// ---------- dtype-agnostic load/store helpers (bf = 1 -> packed bf16) ----------
__device__ __forceinline__ float ub2f(unsigned short u) {
  union { float f; unsigned v; } c; c.v = ((unsigned)u) << 16; return c.f;
}
__device__ __forceinline__ unsigned short f2ub(float f) {
  union { float f; unsigned v; } c; c.f = f;
  unsigned v = c.v;
  return (unsigned short)((v + 0x7FFFu + ((v >> 16) & 1u)) >> 16);  // RNE
}
__device__ __forceinline__ float ld1(const void* p, size_t i, int bf) {
  return bf ? ub2f(((const unsigned short*)p)[i]) : ((const float*)p)[i];
}
__device__ __forceinline__ void ld4(const void* p, size_t i, int bf, float* o) {
  if (bf) {
    ushort4 v = *(const ushort4*)((const unsigned short*)p + i);
    o[0] = ub2f(v.x); o[1] = ub2f(v.y); o[2] = ub2f(v.z); o[3] = ub2f(v.w);
  } else {
    float4 v = *(const float4*)((const float*)p + i);
    o[0] = v.x; o[1] = v.y; o[2] = v.z; o[3] = v.w;
  }
}
__device__ __forceinline__ void st1(void* p, size_t i, int bf, float v) {
  if (bf) ((unsigned short*)p)[i] = f2ub(v);
  else    ((float*)p)[i] = v;
}

// ---------- 0: dtype probe ----------
// fp32 N(0,1): bits 7..14 are mantissa -> ~6% land in [118,132].
// bf16-packed: low ushort is a bf16; bits 7..14 are its exponent -> ~99.8% in [118,132].
__global__ void k_detect(const void* __restrict__ enc, int* __restrict__ flag) {
  const unsigned* u = (const unsigned*)enc;
  unsigned x = u[threadIdx.x];
  unsigned e = (x >> 7) & 0xFFu;
  bool hit = (e >= 118u && e <= 132u);
  unsigned long long b = __ballot(hit);
  if (threadIdx.x == 0) *flag = (__popcll(b) > 32) ? 1 : 0;
}

// ---------- 1: s1[m,a] = tanh(sum_k HV[m,k] * W1[a,k]),  M=65536, N=350(pad 384), K=1536 ----------
__global__ __launch_bounds__(256) void k_s1(const void* __restrict__ enc,
                                            const void* __restrict__ cat,
                                            const void* __restrict__ W1,
                                            float* __restrict__ s1,
                                            const int* __restrict__ flagp) {
  const int bf = *flagp;
  __shared__ float As[16][64];   // [k][m], row stride 64 keeps float4-aligned reads
  __shared__ float Bs[16][64];   // [k][a]
  const int tid = threadIdx.x;
  const int a0 = blockIdx.x * 64;
  const int m0 = blockIdx.y * 64;
  const int tx = tid & 15, ty = tid >> 4;
  float acc[4][4] = {};
  for (int k0 = 0; k0 < D3; k0 += 16) {
    {
      const int moff = tid >> 2;
      const int koff = (tid & 3) * 4;
      const int m = m0 + moff;
      const int k = k0 + koff;
      float o[4];
      if (k < D2) ld4(enc, (size_t)m * D2 + k, bf, o);
      else        ld4(cat, (size_t)(m >> 10) * 512 + (k - D2), bf, o);
      As[koff + 0][moff] = o[0]; As[koff + 1][moff] = o[1];
      As[koff + 2][moff] = o[2]; As[koff + 3][moff] = o[3];
    }
    {
      const int aoff = tid >> 2;
      const int koff = (tid & 3) * 4;
      const int a = a0 + aoff;
      float o[4] = {0.f, 0.f, 0.f, 0.f};
      if (a < DA_) ld4(W1, (size_t)a * D3 + k0 + koff, bf, o);
      Bs[koff + 0][aoff] = o[0]; Bs[koff + 1][aoff] = o[1];
      Bs[koff + 2][aoff] = o[2]; Bs[koff + 3][aoff] = o[3];
    }
    __syncthreads();
#pragma unroll
    for (int kk = 0; kk < 16; ++kk) {
      float4 ra = *(const float4*)&As[kk][ty * 4];
      float4 rb = *(const float4*)&Bs[kk][tx * 4];
      float a_[4] = {ra.x, ra.y, ra.z, ra.w};
      float b_[4] = {rb.x, rb.y, rb.z, rb.w};
#pragma unroll
      for (int i = 0; i < 4; ++i)
#pragma unroll
        for (int j = 0; j < 4; ++j) acc[i][j] += a_[i] * b_[j];
    }
    __syncthreads();
  }
#pragma unroll
  for (int i = 0; i < 4; ++i) {
    const int m = m0 + ty * 4 + i;
#pragma unroll
    for (int j = 0; j < 4; ++j) {
      const int a = a0 + tx * 4 + j;
      if (a < DA_) s1[(size_t)m * S1LD + a] = tanhf(acc[i][j]);
    }
  }
}

// ---------- 2: scores[b,r,n] = masked( sum_a s1[m,a]*W2[r,a] ) -> Aws (fp32) ----------
__global__ __launch_bounds__(256) void k_s2(const float* __restrict__ s1,
                                            const void* __restrict__ W2,
                                            const int* __restrict__ lens,
                                            float* __restrict__ Aws,
                                            const int* __restrict__ flagp) {
  const int bf = *flagp;
  __shared__ float w2s[R_ * DA_];  // 42 KB
  for (int i = threadIdx.x; i < R_ * DA_; i += 256) w2s[i] = ld1(W2, i, bf);
  __syncthreads();
  const int g = blockIdx.x * 256 + threadIdx.x;
  const int m = g >> 5;       // 32 threads per row (30 active)
  const int r = g & 31;
  if (r >= R_) return;
  const float* row = s1 + (size_t)m * S1LD;
  const float* w = &w2s[r * DA_];
  float acc = 0.f;
#pragma unroll 2
  for (int a = 0; a < DA_; ++a) acc += row[a] * w[a];
  const int b = m >> 10, n = m & 1023;
  const float val = (n < lens[b]) ? acc : -1e9f;
  Aws[((size_t)b * R_ + r) * Nsz + n] = val;
}

// ---------- 3: softmax over n, in-place on Aws; also emit A output (dtype-converted) ----------
__global__ __launch_bounds__(256) void k_softmax(float* __restrict__ Aws,
                                                 void* __restrict__ dout,
                                                 const int* __restrict__ flagp) {
  const int bf = *flagp;
  const int row = blockIdx.x;  // b*30 + r, 1920 rows
  float* p = Aws + (size_t)row * Nsz;
  const int tid = threadIdx.x;
  float4 v = ((const float4*)p)[tid];
  float mx = fmaxf(fmaxf(v.x, v.y), fmaxf(v.z, v.w));
#pragma unroll
  for (int off = 1; off < 64; off <<= 1) mx = fmaxf(mx, __shfl_xor(mx, off));
  __shared__ float sred[4], sred2[4];
  if ((tid & 63) == 0) sred[tid >> 6] = mx;
  __syncthreads();
  mx = fmaxf(fmaxf(sred[0], sred[1]), fmaxf(sred[2], sred[3]));
  float e0 = __expf(v.x - mx), e1 = __expf(v.y - mx);
  float e2 = __expf(v.z - mx), e3 = __expf(v.w - mx);
  float s = e0 + e1 + e2 + e3;
#pragma unroll
  for (int off = 1; off < 64; off <<= 1) s += __shfl_xor(s, off);
  if ((tid & 63) == 0) sred2[tid >> 6] = s;
  __syncthreads();
  s = sred2[0] + sred2[1] + sred2[2] + sred2[3];
  const float inv = 1.0f / s;
  const float o0 = e0 * inv, o1 = e1 * inv, o2 = e2 * inv, o3 = e3 * inv;
  ((float4*)p)[tid] = make_float4(o0, o1, o2, o3);
  const size_t base = (size_t)Bsz * MLPH + (size_t)row * Nsz + (size_t)tid * 4;
  st1(dout, base + 0, bf, o0); st1(dout, base + 1, bf, o1);
  st1(dout, base + 2, bf, o2); st1(dout, base + 3, bf, o3);
}

// ---------- 4: M[b,r,d] = sum_n A[b,r,n] * HV[b,n,d] ----------
__global__ __launch_bounds__(256) void k_M(const float* __restrict__ Aws,
                                           const void* __restrict__ enc,
                                           const void* __restrict__ cat,
                                           float* __restrict__ Mf,
                                           const int* __restrict__ flagp) {
  const int bf = *flagp;
  const int b = blockIdx.y;
  const int d0 = blockIdx.x * 128;
  const int tid = threadIdx.x;
  const int dcol = d0 + (tid & 127);
  const int half = tid >> 7;  // 0/1 -> r in [half*15, half*15+15)
  __shared__ float Ash[R_][64];
  float acc[15] = {};
  const float* Ab = Aws + (size_t)b * R_ * Nsz;
  for (int n0 = 0; n0 < Nsz; n0 += 64) {
    for (int idx = tid; idx < R_ * 64; idx += 256) {
      const int r = idx >> 6, nn = idx & 63;
      Ash[r][nn] = Ab[(size_t)r * Nsz + n0 + nn];
    }
    __syncthreads();
    if (dcol < D2) {
      const size_t base = ((size_t)b * Nsz + n0) * D2 + dcol;
      for (int nn = 0; nn < 64; ++nn) {
        const float hv = ld1(enc, base + (size_t)nn * D2, bf);
#pragma unroll
        for (int i = 0; i < 15; ++i) acc[i] += Ash[half * 15 + i][nn] * hv;
      }
    } else {
      const float hv = ld1(cat, (size_t)b * 512 + (dcol - D2), bf);
      for (int nn = 0; nn < 64; ++nn) {
#pragma unroll
        for (int i = 0; i < 15; ++i) acc[i] += Ash[half * 15 + i][nn] * hv;
      }
    }
    __syncthreads();
  }
#pragma unroll
  for (int i = 0; i < 15; ++i) {
    const int r = half * 15 + i;
    Mf[((size_t)b * R_ + r) * D3 + dcol] = acc[i];
  }
}

// ---------- 5: split-K MLP GEMM: part[kb][b][j] = sum_{k in chunk} M[b,k] * W_mlp[j,k] ----------
__global__ __launch_bounds__(256) void k_mlp(const float* __restrict__ Mf,   // [64][46080] fp32
                                             const void* __restrict__ Wm,   // [2048][46080]
                                             float* __restrict__ part,      // [4][64][2048]
                                             const int* __restrict__ flagp) {
  const int bf = *flagp;
  const int j0 = blockIdx.x * 32;
  const int kb = blockIdx.y;
  const int kbeg = kb * (KMLP / 4);
  const int kend = kbeg + (KMLP / 4);
  __shared__ float Ms[32][64];  // [k][b]
  __shared__ float Ws[32][32];  // [k][j]
  const int tid = threadIdx.x;
  const int tx = tid & 15, ty = tid >> 4;
  float acc[4][2] = {};
  for (int k0 = kbeg; k0 < kend; k0 += 32) {
    {
      const int boff = tid >> 3;
      const int koff = (tid & 7) * 4;
#pragma unroll
      for (int p = 0; p < 2; ++p) {
        const int bb = boff + p * 32;
        float4 v = *(const float4*)(Mf + (size_t)bb * KMLP + k0 + koff);
        Ms[koff + 0][bb] = v.x; Ms[koff + 1][bb] = v.y;
        Ms[koff + 2][bb] = v.z; Ms[koff + 3][bb] = v.w;
      }
    }
    {
      const int joff = tid >> 3;
      const int koff = (tid & 7) * 4;
      float o[4];
      ld4(Wm, (size_t)(j0 + joff) * KMLP + k0 + koff, bf, o);
      Ws[koff + 0][joff] = o[0]; Ws[koff + 1][joff] = o[1];
      Ws[koff + 2][joff] = o[2]; Ws[koff + 3][joff] = o[3];
    }
    __syncthreads();
#pragma unroll
    for (int kk = 0; kk < 32; ++kk) {
      float4 rm = *(const float4*)&Ms[kk][ty * 4];
      const float w0 = Ws[kk][tx * 2], w1 = Ws[kk][tx * 2 + 1];
      acc[0][0] += rm.x * w0; acc[0][1] += rm.x * w1;
      acc[1][0] += rm.y * w0; acc[1][1] += rm.y * w1;
      acc[2][0] += rm.z * w0; acc[2][1] += rm.z * w1;
      acc[3][0] += rm.w * w0; acc[3][1] += rm.w * w1;
    }
    __syncthreads();
  }
#pragma unroll
  for (int i = 0; i < 4; ++i) {
    const int bb = ty * 4 + i;
    part[((size_t)kb * Bsz + bb) * MLPH + j0 + tx * 2 + 0] = acc[i][0];
    part[((size_t)kb * Bsz + bb) * MLPH + j0 + tx * 2 + 1] = acc[i][1];
  }
}

// ---------- 6: out[b,j] = b_mlp[j] + sum_kb part[kb][b][j] ----------
__global__ __launch_bounds__(256) void k_out(const float* __restrict__ part,
                                             const void* __restrict__ bias,
                                             void* __restrict__ dout,
                                             const int* __restrict__ flagp) {
  const int bf = *flagp;
  const int g = blockIdx.x * 256 + threadIdx.x;  // < 131072
  const int j = g & (MLPH - 1);
  const float v = ld1(bias, j, bf) + part[g] + part[131072 + g] +
                  part[262144 + g] + part[393216 + g];
  st1(dout, g, bf, v);
}

extern "C" void kernel_launch(void* const* d_in, const int* in_sizes, int n_in,
                              void* d_out, int out_size, void* d_ws, size_t ws_size,
                              hipStream_t stream) {
  const void* enc  = d_in[0];                 // [64,1024,1024]
  const int*  lens = (const int*)d_in[1];     // [64]
  const void* cat  = d_in[3];                 // [64,1,512]
  const void* W1   = d_in[4];                 // [350,1536]
  const void* W2   = d_in[5];                 // [30,350]
  const void* Wm   = d_in[6];                 // [2048,46080]
  const void* bmlp = d_in[7];                 // [2048]

  // workspace layout (needs ~114.1 MB)
  char*  wsb  = (char*)d_ws;
  int*   flag = (int*)wsb;
  float* s1   = (float*)(wsb + 1024);                    // 65536*352 fp32 = 92.27 MB
  float* Aws  = s1 + (size_t)65536 * S1LD;               // 64*30*1024 fp32 = 7.86 MB
  float* Mf   = Aws + (size_t)Bsz * R_ * Nsz;            // 64*46080 fp32 = 11.80 MB
  float* part = Mf + (size_t)Bsz * KMLP;                 // 4*64*2048 fp32 = 2.10 MB

  k_detect <<<1, 64, 0, stream>>>(enc, flag);
  k_s1     <<<dim3(6, 1024), 256, 0, stream>>>(enc, cat, W1, s1, flag);
  k_s2     <<<8192, 256, 0, stream>>>(s1, W2, lens, Aws, flag);
  k_softmax<<<Bsz * R_, 256, 0, stream>>>(Aws, d_out, flag);
  k_M      <<<dim3(12, Bsz), 256, 0, stream>>>(Aws, enc, cat, Mf, flag);
  k_mlp    <<<dim3(MLPH / 32, 4), 256, 0, stream>>>(Mf, Wm, part, flag);
  k_out    <<<512, 256, 0, stream>>>(part, bmlp, d_out, flag);
}